// Round 4
// baseline (1396.323 us; speedup 1.0000x reference)
//
#include <hip/hip_runtime.h>

#define B_ 4
#define T_ 2048
#define D_ 1024
#define HS_ 64

typedef __attribute__((ext_vector_type(4))) float f32x4;
typedef __attribute__((ext_vector_type(8))) short bf16x8;
typedef __attribute__((ext_vector_type(4))) unsigned short u16x4;
typedef __attribute__((ext_vector_type(4))) unsigned int u32x4;

__device__ __forceinline__ unsigned short f2bf(float f) {
  unsigned int u = __float_as_uint(f);
  u += 0x7FFFu + ((u >> 16) & 1u);   // RNE
  return (unsigned short)(u >> 16);
}

// ---------------------------------------------------------------------------
// kconv: transposed bf16 hi/lo split weights wT[192][1024].
// cols 0-63 = wq, 64-127 = 8*wk (score scale folded), 128-191 = wv.
// ---------------------------------------------------------------------------
__global__ void kconv_kernel(const float* __restrict__ wq, const float* __restrict__ wk,
                             const float* __restrict__ wv,
                             unsigned short* __restrict__ wTh, unsigned short* __restrict__ wTl) {
  int gid = blockIdx.x * 256 + threadIdx.x;   // < 192*1024
  int n = gid >> 10, d = gid & 1023;
  float v;
  if (n < 64)        v = wq[d * 64 + n];
  else if (n < 128)  v = 8.0f * wk[d * 64 + (n - 64)];
  else               v = wv[d * 64 + (n - 128)];
  unsigned short h = f2bf(v);
  wTh[gid] = h;
  wTl[gid] = f2bf(v - __uint_as_float(((unsigned int)h) << 16));
}

// ---------------------------------------------------------------------------
// kproj: C[8192][192] = x * wcat via split-bf16 MFMA (fp32-grade).
// qw fp32 [B][T][64], k8w fp32 (pre-scaled by 8), vbw bf16 [B][T][64].
// ---------------------------------------------------------------------------
__global__ __launch_bounds__(256) void kproj_kernel(
    const float* __restrict__ x, const unsigned short* __restrict__ wTh,
    const unsigned short* __restrict__ wTl,
    const float* __restrict__ bq, const float* __restrict__ bk, const float* __restrict__ bv,
    float* __restrict__ qw, float* __restrict__ k8w, unsigned short* __restrict__ vbw) {
  __shared__ unsigned short xh[32 * 32], xl[32 * 32];
  __shared__ unsigned short wh[192 * 32], wl[192 * 32];
  const int tid = threadIdx.x;
  const int m0 = blockIdx.x * 32;
  const int lane = tid & 63, wid = tid >> 6;
  const int mf = wid & 1, np = wid >> 1;
  const int r15 = lane & 15, u = lane >> 4;

  f32x4 xv;
  f32x4 wvh[3], wvl[3];
  auto issue = [&](int k0) {
    xv = *(const f32x4*)&x[(m0 + (tid >> 3)) * 1024 + k0 + (tid & 7) * 4];
#pragma unroll
    for (int i = 0; i < 3; ++i) {
      int c8 = i * 256 + tid;
      wvh[i] = *(const f32x4*)&wTh[(c8 >> 2) * 1024 + k0 + (c8 & 3) * 8];
      wvl[i] = *(const f32x4*)&wTl[(c8 >> 2) * 1024 + k0 + (c8 & 3) * 8];
    }
  };
  auto commit = [&]() {
    u16x4 hhv, llv;
#pragma unroll
    for (int c = 0; c < 4; ++c) {
      unsigned short h = f2bf(xv[c]);
      hhv[c] = h;
      llv[c] = f2bf(xv[c] - __uint_as_float(((unsigned int)h) << 16));
    }
    *(u16x4*)&xh[(tid >> 3) * 32 + (tid & 7) * 4] = hhv;
    *(u16x4*)&xl[(tid >> 3) * 32 + (tid & 7) * 4] = llv;
#pragma unroll
    for (int i = 0; i < 3; ++i) {
      int c8 = i * 256 + tid;
      *(f32x4*)&wh[c8 * 8] = wvh[i];
      *(f32x4*)&wl[c8 * 8] = wvl[i];
    }
  };

  f32x4 z = {0.f, 0.f, 0.f, 0.f};
  f32x4 acc[6] = {z, z, z, z, z, z};
  issue(0);
  for (int kt = 0; kt < 32; ++kt) {
    __syncthreads();
    commit();
    __syncthreads();
    if (kt + 1 < 32) issue((kt + 1) * 32);
    bf16x8 ah = *(const bf16x8*)&xh[(mf * 16 + r15) * 32 + u * 8];
    bf16x8 al = *(const bf16x8*)&xl[(mf * 16 + r15) * 32 + u * 8];
#pragma unroll
    for (int nf = 0; nf < 6; ++nf) {
      int nr = np * 96 + nf * 16 + r15;
      bf16x8 bh = *(const bf16x8*)&wh[nr * 32 + u * 8];
      bf16x8 bl = *(const bf16x8*)&wl[nr * 32 + u * 8];
      acc[nf] = __builtin_amdgcn_mfma_f32_16x16x32_bf16(ah, bh, acc[nf], 0, 0, 0);
      acc[nf] = __builtin_amdgcn_mfma_f32_16x16x32_bf16(ah, bl, acc[nf], 0, 0, 0);
      acc[nf] = __builtin_amdgcn_mfma_f32_16x16x32_bf16(al, bh, acc[nf], 0, 0, 0);
    }
  }
#pragma unroll
  for (int nf = 0; nf < 6; ++nf) {
    const int n = np * 96 + nf * 16 + r15;
#pragma unroll
    for (int r = 0; r < 4; ++r) {
      const int m = m0 + mf * 16 + u * 4 + r;
      float val = acc[nf][r];
      if (n < 64) {
        qw[m * 64 + n] = val + bq[n];
      } else if (n < 128) {
        k8w[m * 64 + (n - 64)] = val + 8.0f * bk[n - 64];
      } else {
        int h = n - 128;
        vbw[m * 64 + h] = f2bf(val + bv[h]);
      }
    }
  }
}

// ---------------------------------------------------------------------------
// kfused: flash attention over one v-quarter (512 v). Block = 8 t x 4 b.
// 16 v per phase (32 phases, 2 barriers each). Single-buffer LDS (k8 f32,
// V bf16 chunk-XOR swizzled). rel direct global->reg (single-consumer),
// T14 consume-then-reissue. T13 defer-rescale (THR=5). 3 blocks/CU target.
// ---------------------------------------------------------------------------
__global__ __launch_bounds__(256, 3) void kfused(
    const float* __restrict__ qw, const float* __restrict__ k8w,
    const unsigned short* __restrict__ vbw, const float* __restrict__ rel,
    float* __restrict__ Oh, float* __restrict__ ml2) {
  __shared__ float kl[64 * 68];            // [b*16+vv][68] f32      17408 B
  __shared__ unsigned short vt_[64 * 80];  // [b*16+vv][80] bf16     10240 B
  const int tid = threadIdx.x;
  const int tt = blockIdx.x >> 2, vq = blockIdx.x & 3;
  const int t0 = tt * 8;
  const int vbase = vq * 512;
  const int wid = tid >> 6;
  const int tl = (tid >> 5) & 1;
  const int vl = (tid >> 2) & 7;
  const int hq = tid & 3;
  const int tloc = wid * 2 + tl;
  const int tg = t0 + tloc;

  // q in registers: 4 batches x this lane's h-quarter (16 h)
  f32x4 qr[4][4];
#pragma unroll
  for (int b = 0; b < 4; ++b)
#pragma unroll
    for (int j = 0; j < 4; ++j)
      qr[b][j] = *(const f32x4*)&qw[((b << 11) + tg) * 64 + hq * 16 + j * 4];

  const float* relrow = rel + (size_t)tg * 131072 + hq * 16;

  f32x4 rA[8];     // rel for (vl, vl+8) of one phase
  f32x4 stk[4];    // k8 staging (16 KB tile / 256 thr)
  f32x4 stv[2];    // V staging  ( 8 KB tile / 256 thr)

#define ISSUE_REL(VT) do {                                                  \
    const float* p0_ = relrow + (size_t)((VT) + vl) * 64;                   \
    const float* p1_ = relrow + (size_t)((VT) + vl + 8) * 64;               \
    rA[0] = *(const f32x4*)(p0_);      rA[1] = *(const f32x4*)(p0_ + 4);    \
    rA[2] = *(const f32x4*)(p0_ + 8);  rA[3] = *(const f32x4*)(p0_ + 12);   \
    rA[4] = *(const f32x4*)(p1_);      rA[5] = *(const f32x4*)(p1_ + 4);    \
    rA[6] = *(const f32x4*)(p1_ + 8);  rA[7] = *(const f32x4*)(p1_ + 12);   \
  } while (0)

#define ISSUE_KV(VT) do {                                                   \
    _Pragma("unroll")                                                       \
    for (int i = 0; i < 4; ++i) {                                           \
      int c4 = i * 256 + tid; int pr = c4 >> 4; int c = c4 & 15;            \
      stk[i] = *(const f32x4*)&k8w[(pr >> 4) * 131072 +                     \
                                   ((VT) + (pr & 15)) * 64 + c * 4];        \
    }                                                                       \
    _Pragma("unroll")                                                       \
    for (int i = 0; i < 2; ++i) {                                           \
      int c8 = i * 256 + tid; int pr = c8 >> 3; int cc = c8 & 7;            \
      stv[i] = *(const f32x4*)&vbw[((pr >> 4) * 2048 + (VT) + (pr & 15))    \
                                   * 64 + cc * 8];                          \
    }                                                                       \
  } while (0)

#define COMMIT_KV() do {                                                    \
    _Pragma("unroll")                                                       \
    for (int i = 0; i < 4; ++i) {                                           \
      int c4 = i * 256 + tid; int pr = c4 >> 4; int c = c4 & 15;            \
      *(f32x4*)&kl[pr * 68 + c * 4] = stk[i];                               \
    }                                                                       \
    _Pragma("unroll")                                                       \
    for (int i = 0; i < 2; ++i) {                                           \
      int c8 = i * 256 + tid; int pr = c8 >> 3; int cc = c8 & 7;            \
      int sw = cc ^ (pr >> 4);            /* chunk-XOR by b: bank spread */ \
      *(f32x4*)&vt_[pr * 80 + sw * 8] = stv[i];                             \
    }                                                                       \
  } while (0)

#define SCORE(OFF, VLOC, SOUT) do {                                         \
    f32x4 z4 = {0.f,0.f,0.f,0.f};                                           \
    f32x4 a0 = z4, a1 = z4, a2 = z4, a3 = z4;                               \
    const float* krow = &kl[(VLOC) * 68];                                   \
    _Pragma("unroll")                                                       \
    for (int j = 0; j < 4; ++j) {                                           \
      int c = hq * 16 + j * 4;                                              \
      f32x4 r4 = rA[(OFF) + j];                                             \
      f32x4 kb0 = *(const f32x4*)&krow[c];                                  \
      f32x4 kb1 = *(const f32x4*)&krow[1088 + c];                           \
      f32x4 kb2 = *(const f32x4*)&krow[2176 + c];                           \
      f32x4 kb3 = *(const f32x4*)&krow[3264 + c];                           \
      a0 += qr[0][j] * (kb0 + r4);                                          \
      a1 += qr[1][j] * (kb1 + r4);                                          \
      a2 += qr[2][j] * (kb2 + r4);                                          \
      a3 += qr[3][j] * (kb3 + r4);                                          \
    }                                                                       \
    float s0 = a0[0] + a0[1] + a0[2] + a0[3];                               \
    float s1 = a1[0] + a1[1] + a1[2] + a1[3];                               \
    float s2 = a2[0] + a2[1] + a2[2] + a2[3];                               \
    float s3 = a3[0] + a3[1] + a3[2] + a3[3];                               \
    s0 += __shfl_xor(s0, 1); s0 += __shfl_xor(s0, 2);                       \
    s1 += __shfl_xor(s1, 1); s1 += __shfl_xor(s1, 2);                       \
    s2 += __shfl_xor(s2, 1); s2 += __shfl_xor(s2, 2);                       \
    s3 += __shfl_xor(s3, 1); s3 += __shfl_xor(s3, 2);                       \
    SOUT = (hq == 0) ? s0 : (hq == 1) ? s1 : (hq == 2) ? s2 : s3;           \
  } while (0)

#define PVACC(P, VLOC) do {                                                 \
    const unsigned short* vrow = &vt_[(hq * 16 + (VLOC)) * 80];             \
    _Pragma("unroll")                                                       \
    for (int k = 0; k < 8; ++k) {                                           \
      int kk = k ^ hq;                                                      \
      u32x4 uu = *(const u32x4*)&vrow[kk * 8];                              \
      _Pragma("unroll")                                                     \
      for (int w = 0; w < 4; ++w) {                                         \
        float lo = __uint_as_float(uu[w] << 16);                            \
        float hi = __uint_as_float(uu[w] & 0xffff0000u);                    \
        o[k * 8 + w * 2]     = fmaf((P), lo, o[k * 8 + w * 2]);             \
        o[k * 8 + w * 2 + 1] = fmaf((P), hi, o[k * 8 + w * 2 + 1]);         \
      }                                                                     \
    }                                                                       \
  } while (0)

  float o[64];
#pragma unroll
  for (int h = 0; h < 64; ++h) o[h] = 0.0f;
  float mrun = -3.0e38f, lrun = 0.0f;

  ISSUE_KV(vbase);
  ISSUE_REL(vbase);
  COMMIT_KV();
  __syncthreads();

  for (int ph = 0; ph < 32; ++ph) {
    const int vt = vbase + ph * 16;
    const bool more = (ph + 1 < 32);
    if (more) ISSUE_KV(vt + 16);            // next k/V tile -> regs, in flight
    float sA, sB;
    SCORE(0, vl, sA);
    SCORE(4, vl + 8, sB);
    if (more) ISSUE_REL(vt + 16);           // rA consumed; refill (T14)
    // ---- online softmax, deferred rescale (T13)
    float mx = fmaxf(sA, sB);
    mx = fmaxf(mx, __shfl_xor(mx, 4));
    mx = fmaxf(mx, __shfl_xor(mx, 8));
    mx = fmaxf(mx, __shfl_xor(mx, 16));
    if (__any(mx > mrun + 5.0f)) {
      float mnew = fmaxf(mrun, mx);
      float alpha = __expf(mrun - mnew);
      lrun *= alpha;
#pragma unroll
      for (int h = 0; h < 64; ++h) o[h] *= alpha;
      mrun = mnew;
    }
    float p0 = __expf(sA - mrun);
    float p1 = __expf(sB - mrun);
    float ps = p0 + p1;
    ps += __shfl_xor(ps, 4);
    ps += __shfl_xor(ps, 8);
    ps += __shfl_xor(ps, 16);
    lrun += ps;
    PVACC(p0, vl);
    PVACC(p1, vl + 8);
    __syncthreads();                        // all reads of kl/vt_ done
    if (more) COMMIT_KV();
    __syncthreads();                        // new tile visible
  }

  // ---- reduce-scatter O over the 8 v-lanes: lane vl ends with o[vl*8..+7]
  float n32[32];
#pragma unroll
  for (int j = 0; j < 32; ++j) {
    float send = (vl & 4) ? o[j] : o[j + 32];
    float t = __shfl_xor(send, 16);
    float keep = (vl & 4) ? o[j + 32] : o[j];
    n32[j] = keep + t;
  }
  float n16[16];
#pragma unroll
  for (int j = 0; j < 16; ++j) {
    float send = (vl & 2) ? n32[j] : n32[j + 16];
    float t = __shfl_xor(send, 8);
    float keep = (vl & 2) ? n32[j + 16] : n32[j];
    n16[j] = keep + t;
  }
  float n8[8];
#pragma unroll
  for (int j = 0; j < 8; ++j) {
    float send = (vl & 1) ? n16[j] : n16[j + 8];
    float t = __shfl_xor(send, 4);
    float keep = (vl & 1) ? n16[j + 8] : n16[j];
    n8[j] = keep + t;
  }

  const int orow = hq * 2048 + tg;
  float* Ohq = Oh + (size_t)vq * 524288;
  f32x4 w0 = {n8[0], n8[1], n8[2], n8[3]};
  f32x4 w1 = {n8[4], n8[5], n8[6], n8[7]};
  *(f32x4*)&Ohq[orow * 64 + vl * 8] = w0;
  *(f32x4*)&Ohq[orow * 64 + vl * 8 + 4] = w1;
  if (vl == 0) {
    ml2[(vq * 8192 + orow) * 2] = mrun;
    ml2[(vq * 8192 + orow) * 2 + 1] = lrun;
  }
#undef ISSUE_REL
#undef ISSUE_KV
#undef COMMIT_KV
#undef SCORE
#undef PVACC
}

// ---------------------------------------------------------------------------
// kcomb: merge the four v-quarter partials.
// ---------------------------------------------------------------------------
__global__ __launch_bounds__(256) void kcomb(
    const float* __restrict__ Oh, const float* __restrict__ ml2,
    float* __restrict__ O) {
  int gid = blockIdx.x * 256 + threadIdx.x;    // 8192 rows * 16 h-quads
  int row = gid >> 4, hc = gid & 15;
  float mq[4], lq[4];
  float m = -3.0e38f;
#pragma unroll
  for (int q = 0; q < 4; ++q) {
    mq[q] = ml2[(q * 8192 + row) * 2];
    lq[q] = ml2[(q * 8192 + row) * 2 + 1];
    m = fmaxf(m, mq[q]);
  }
  float den = 0.0f;
  f32x4 acc = {0.f, 0.f, 0.f, 0.f};
#pragma unroll
  for (int q = 0; q < 4; ++q) {
    float c = __expf(mq[q] - m);
    den = fmaf(c, lq[q], den);
    f32x4 oq = *(const f32x4*)&Oh[(size_t)q * 524288 + row * 64 + hc * 4];
#pragma unroll
    for (int j = 0; j < 4; ++j) acc[j] = fmaf(c, oq[j], acc[j]);
  }
  float inv = 1.0f / den;
  f32x4 r;
#pragma unroll
  for (int j = 0; j < 4; ++j) r[j] = acc[j] * inv;
  *(f32x4*)&O[row * 64 + hc * 4] = r;
}

// ---------------------------------------------------------------------------
extern "C" void kernel_launch(void* const* d_in, const int* in_sizes, int n_in,
                              void* d_out, int out_size, void* d_ws, size_t ws_size,
                              hipStream_t stream) {
  const float* x   = (const float*)d_in[0];
  const float* wq  = (const float*)d_in[1];
  const float* bq  = (const float*)d_in[2];
  const float* wk  = (const float*)d_in[3];
  const float* bk  = (const float*)d_in[4];
  const float* wv  = (const float*)d_in[5];
  const float* bv  = (const float*)d_in[6];
  const float* rel = (const float*)d_in[7];
  float* O = (float*)d_out;

  char* ws = (char*)d_ws;
  float* qw            = (float*)(ws);                       // 2,097,152 B
  float* k8w           = (float*)(ws + 2097152);             // 2,097,152 B
  unsigned short* vbw  = (unsigned short*)(ws + 4194304);    // 1,048,576 B
  unsigned short* wTh  = (unsigned short*)(ws + 5242880);    //   393,216 B
  unsigned short* wTl  = (unsigned short*)(ws + 5636096);    //   393,216 B
  float* Oh            = (float*)(ws + 6291456);             // 8,388,608 B (4 quarters)
  float* ml2           = (float*)(ws + 14680064);            //   262,144 B
  // total ws usage: ~14.9 MB

  kconv_kernel<<<dim3(768), dim3(256), 0, stream>>>(wq, wk, wv, wTh, wTl);
  kproj_kernel<<<dim3(256), dim3(256), 0, stream>>>(x, wTh, wTl, bq, bk, bv, qw, k8w, vbw);
  kfused<<<dim3(1024), dim3(256), 0, stream>>>(qw, k8w, vbw, rel, Oh, ml2);
  kcomb<<<dim3(512), dim3(256), 0, stream>>>(Oh, ml2, O);
}

// Round 5
// 381.252 us; speedup vs baseline: 3.6625x; 3.6625x over previous
//
#include <hip/hip_runtime.h>

#define B_ 4
#define T_ 2048
#define D_ 1024
#define HS_ 64

typedef __attribute__((ext_vector_type(4))) float f32x4;
typedef __attribute__((ext_vector_type(8))) short bf16x8;
typedef __attribute__((ext_vector_type(4))) unsigned short u16x4;
typedef __attribute__((ext_vector_type(4))) unsigned int u32x4;

__device__ __forceinline__ unsigned short f2bf(float f) {
  unsigned int u = __float_as_uint(f);
  u += 0x7FFFu + ((u >> 16) & 1u);   // RNE
  return (unsigned short)(u >> 16);
}
__device__ __forceinline__ float bf2f(unsigned short s) {
  return __uint_as_float(((unsigned int)s) << 16);
}

// ---------------------------------------------------------------------------
// kconv: transposed bf16 hi/lo split weights wT[192][1024].
// cols 0-63 = wq, 64-127 = 8*wk (score scale folded), 128-191 = wv.
// ---------------------------------------------------------------------------
__global__ void kconv_kernel(const float* __restrict__ wq, const float* __restrict__ wk,
                             const float* __restrict__ wv,
                             unsigned short* __restrict__ wTh, unsigned short* __restrict__ wTl) {
  int gid = blockIdx.x * 256 + threadIdx.x;   // < 192*1024
  int n = gid >> 10, d = gid & 1023;
  float v;
  if (n < 64)        v = wq[d * 64 + n];
  else if (n < 128)  v = 8.0f * wk[d * 64 + (n - 64)];
  else               v = wv[d * 64 + (n - 128)];
  unsigned short h = f2bf(v);
  wTh[gid] = h;
  wTl[gid] = f2bf(v - __uint_as_float(((unsigned int)h) << 16));
}

// ---------------------------------------------------------------------------
// kproj: C[8192][192] = x * wcat via split-bf16 MFMA (fp32-grade).
// qw fp32 [B][T][64], k8w fp32 (pre-scaled by 8), vbw bf16 [B][T][64].
// ---------------------------------------------------------------------------
__global__ __launch_bounds__(256) void kproj_kernel(
    const float* __restrict__ x, const unsigned short* __restrict__ wTh,
    const unsigned short* __restrict__ wTl,
    const float* __restrict__ bq, const float* __restrict__ bk, const float* __restrict__ bv,
    float* __restrict__ qw, float* __restrict__ k8w, unsigned short* __restrict__ vbw) {
  __shared__ unsigned short xh[32 * 32], xl[32 * 32];
  __shared__ unsigned short wh[192 * 32], wl[192 * 32];
  const int tid = threadIdx.x;
  const int m0 = blockIdx.x * 32;
  const int lane = tid & 63, wid = tid >> 6;
  const int mf = wid & 1, np = wid >> 1;
  const int r15 = lane & 15, u = lane >> 4;

  f32x4 xv;
  f32x4 wvh[3], wvl[3];
  auto issue = [&](int k0) {
    xv = *(const f32x4*)&x[(m0 + (tid >> 3)) * 1024 + k0 + (tid & 7) * 4];
#pragma unroll
    for (int i = 0; i < 3; ++i) {
      int c8 = i * 256 + tid;
      wvh[i] = *(const f32x4*)&wTh[(c8 >> 2) * 1024 + k0 + (c8 & 3) * 8];
      wvl[i] = *(const f32x4*)&wTl[(c8 >> 2) * 1024 + k0 + (c8 & 3) * 8];
    }
  };
  auto commit = [&]() {
    u16x4 hhv, llv;
#pragma unroll
    for (int c = 0; c < 4; ++c) {
      unsigned short h = f2bf(xv[c]);
      hhv[c] = h;
      llv[c] = f2bf(xv[c] - __uint_as_float(((unsigned int)h) << 16));
    }
    *(u16x4*)&xh[(tid >> 3) * 32 + (tid & 7) * 4] = hhv;
    *(u16x4*)&xl[(tid >> 3) * 32 + (tid & 7) * 4] = llv;
#pragma unroll
    for (int i = 0; i < 3; ++i) {
      int c8 = i * 256 + tid;
      *(f32x4*)&wh[c8 * 8] = wvh[i];
      *(f32x4*)&wl[c8 * 8] = wvl[i];
    }
  };

  f32x4 z = {0.f, 0.f, 0.f, 0.f};
  f32x4 acc[6] = {z, z, z, z, z, z};
  issue(0);
  for (int kt = 0; kt < 32; ++kt) {
    __syncthreads();
    commit();
    __syncthreads();
    if (kt + 1 < 32) issue((kt + 1) * 32);
    bf16x8 ah = *(const bf16x8*)&xh[(mf * 16 + r15) * 32 + u * 8];
    bf16x8 al = *(const bf16x8*)&xl[(mf * 16 + r15) * 32 + u * 8];
#pragma unroll
    for (int nf = 0; nf < 6; ++nf) {
      int nr = np * 96 + nf * 16 + r15;
      bf16x8 bh = *(const bf16x8*)&wh[nr * 32 + u * 8];
      bf16x8 bl = *(const bf16x8*)&wl[nr * 32 + u * 8];
      acc[nf] = __builtin_amdgcn_mfma_f32_16x16x32_bf16(ah, bh, acc[nf], 0, 0, 0);
      acc[nf] = __builtin_amdgcn_mfma_f32_16x16x32_bf16(ah, bl, acc[nf], 0, 0, 0);
      acc[nf] = __builtin_amdgcn_mfma_f32_16x16x32_bf16(al, bh, acc[nf], 0, 0, 0);
    }
  }
#pragma unroll
  for (int nf = 0; nf < 6; ++nf) {
    const int n = np * 96 + nf * 16 + r15;
#pragma unroll
    for (int r = 0; r < 4; ++r) {
      const int m = m0 + mf * 16 + u * 4 + r;
      float val = acc[nf][r];
      if (n < 64) {
        qw[m * 64 + n] = val + bq[n];
      } else if (n < 128) {
        k8w[m * 64 + (n - 64)] = val + 8.0f * bk[n - 64];
      } else {
        int h = n - 128;
        vbw[m * 64 + h] = f2bf(val + bv[h]);
      }
    }
  }
}

// ---------------------------------------------------------------------------
// kfused: flash attention over one v-half (R3 dataflow). Per block: 8 t x 4 b.
// T4 barrier protocol: one raw s_barrier per 8-v phase, NO vmcnt(0) drain —
// commit targets the other LDS buffer (its readers finished at the previous
// barrier), so the compiler's use-based vmcnt waits stay counted and rel/kv
// prefetch loads remain in flight across barriers. T13 defer-rescale THR=5.
// Register discipline: (256,2) cap, all arrays statically indexed (rule #20).
// ---------------------------------------------------------------------------
__global__ __launch_bounds__(256, 2) void kfused(
    const float* __restrict__ qw, const float* __restrict__ k8w,
    const unsigned short* __restrict__ vbw, const float* __restrict__ rel,
    float* __restrict__ Oh, float* __restrict__ ml2) {
  __shared__ float kl[2][32 * 68];            // k8 tile  [b*8+v][68]   17408 B
  __shared__ unsigned short vt_[2][32 * 76];  // V tile   [b*8+v][76]    9728 B
  const int tid = threadIdx.x;
  const int tt = blockIdx.x >> 1, vh = blockIdx.x & 1;
  const int t0 = tt * 8;
  const int vbase = vh * 1024;
  const int wid = tid >> 6;
  const int tl = (tid >> 5) & 1;
  const int vl = (tid >> 2) & 7;
  const int hq = tid & 3;
  const int tloc = wid * 2 + tl;
  const int tg = t0 + tloc;

  // q in registers: 4 batches x this lane's h-quarter (16 h)
  f32x4 qr[4][4];
#pragma unroll
  for (int b = 0; b < 4; ++b)
#pragma unroll
    for (int j = 0; j < 4; ++j)
      qr[b][j] = *(const f32x4*)&qw[((b << 11) + tg) * 64 + hq * 16 + j * 4];

  const float* relrow = rel + (size_t)tg * 131072 + hq * 16;

  f32x4 rA[4], rB[4];        // rel ping-pong (per-thread-private data)
  f32x4 stk[2];              // k8 staging
  f32x4 stv;                 // V staging

#define ISSUE_REL(DST, VT) do {                                           \
    const float* p_ = relrow + (size_t)((VT) + vl) * 64;                  \
    DST[0] = *(const f32x4*)(p_);                                         \
    DST[1] = *(const f32x4*)(p_ + 4);                                     \
    DST[2] = *(const f32x4*)(p_ + 8);                                     \
    DST[3] = *(const f32x4*)(p_ + 12);                                    \
  } while (0)

  auto issue_kv = [&](int vt) {
#pragma unroll
    for (int i = 0; i < 2; ++i) {              // k8 tile: 8KB
      int c4 = i * 256 + tid;
      int pr = c4 >> 4, c = c4 & 15;
      stk[i] = *(const f32x4*)&k8w[(pr >> 3) * 131072 + (vt + (pr & 7)) * 64 + c * 4];
    }
    {                                          // V tile (bf16): 4KB
      int pr = tid >> 3, cc = tid & 7;
      stv = *(const f32x4*)&vbw[(((pr >> 3) << 11) + vt + (pr & 7)) * 64 + cc * 8];
    }
  };
  auto commit_kv = [&](int buf) {
#pragma unroll
    for (int i = 0; i < 2; ++i) {
      int c4 = i * 256 + tid;
      int pr = c4 >> 4, c = c4 & 15;
      *(f32x4*)&kl[buf][pr * 68 + c * 4] = stk[i];
    }
    {
      int pr = tid >> 3, cc = tid & 7;
      const u16x4* pv = (const u16x4*)&stv;
      *(u16x4*)&vt_[buf][pr * 76 + cc * 8] = pv[0];
      *(u16x4*)&vt_[buf][pr * 76 + cc * 8 + 4] = pv[1];
    }
  };

  float o[64];
#pragma unroll
  for (int h = 0; h < 64; ++h) o[h] = 0.0f;
  float mrun = -3.0e38f, lrun = 0.0f;

// one barrier per phase: lgkmcnt(0) makes this wave's ds_writes visible,
// raw s_barrier (no compiler vmcnt(0) drain), clobbers pin memory op order.
#define PHASE_BARRIER() do {                                              \
    asm volatile("s_waitcnt lgkmcnt(0)" ::: "memory");                    \
    __builtin_amdgcn_s_barrier();                                         \
    asm volatile("" ::: "memory");                                        \
  } while (0)

#define COMPUTE(RC, BUF) do {                                             \
    f32x4 z4 = {0.f, 0.f, 0.f, 0.f};                                      \
    f32x4 a0 = z4, a1 = z4, a2 = z4, a3 = z4;                             \
    const float* krow = &kl[BUF][vl * 68];                                \
    _Pragma("unroll")                                                     \
    for (int j = 0; j < 4; ++j) {                                         \
      int c = (hq * 4 + j) * 4;                                           \
      f32x4 r4 = RC[j];                                                   \
      f32x4 kb0 = *(const f32x4*)&krow[c];                                \
      f32x4 kb1 = *(const f32x4*)&krow[544 + c];                          \
      f32x4 kb2 = *(const f32x4*)&krow[1088 + c];                         \
      f32x4 kb3 = *(const f32x4*)&krow[1632 + c];                         \
      a0 += qr[0][j] * (kb0 + r4);                                        \
      a1 += qr[1][j] * (kb1 + r4);                                        \
      a2 += qr[2][j] * (kb2 + r4);                                        \
      a3 += qr[3][j] * (kb3 + r4);                                        \
    }                                                                     \
    float s0 = a0[0] + a0[1] + a0[2] + a0[3];                             \
    float s1 = a1[0] + a1[1] + a1[2] + a1[3];                             \
    float s2 = a2[0] + a2[1] + a2[2] + a2[3];                             \
    float s3 = a3[0] + a3[1] + a3[2] + a3[3];                             \
    s0 += __shfl_xor(s0, 1); s0 += __shfl_xor(s0, 2);                     \
    s1 += __shfl_xor(s1, 1); s1 += __shfl_xor(s1, 2);                     \
    s2 += __shfl_xor(s2, 1); s2 += __shfl_xor(s2, 2);                     \
    s3 += __shfl_xor(s3, 1); s3 += __shfl_xor(s3, 2);                     \
    float s = (hq == 0) ? s0 : (hq == 1) ? s1 : (hq == 2) ? s2 : s3;      \
    float mx = s;                                                         \
    mx = fmaxf(mx, __shfl_xor(mx, 4));                                    \
    mx = fmaxf(mx, __shfl_xor(mx, 8));                                    \
    mx = fmaxf(mx, __shfl_xor(mx, 16));                                   \
    if (__any(mx > mrun + 5.0f)) {       /* T13: rescale only on drift */ \
      float mnew = fmaxf(mrun, mx);                                       \
      float alpha = __expf(mrun - mnew);                                  \
      lrun *= alpha;                                                      \
      _Pragma("unroll")                                                   \
      for (int h = 0; h < 64; ++h) o[h] *= alpha;                         \
      mrun = mnew;                                                        \
    }                                                                     \
    float p = __expf(s - mrun);                                           \
    float ps_ = p;                                                        \
    ps_ += __shfl_xor(ps_, 4);                                            \
    ps_ += __shfl_xor(ps_, 8);                                            \
    ps_ += __shfl_xor(ps_, 16);                                           \
    lrun += ps_;                                                          \
    const unsigned short* vrow = &vt_[BUF][(hq * 8 + vl) * 76];           \
    _Pragma("unroll")                                                     \
    for (int k = 0; k < 16; ++k) {                                        \
      u16x4 vv = *(const u16x4*)&vrow[k * 4];                             \
      o[k * 4 + 0] = fmaf(p, bf2f(vv[0]), o[k * 4 + 0]);                  \
      o[k * 4 + 1] = fmaf(p, bf2f(vv[1]), o[k * 4 + 1]);                  \
      o[k * 4 + 2] = fmaf(p, bf2f(vv[2]), o[k * 4 + 2]);                  \
      o[k * 4 + 3] = fmaf(p, bf2f(vv[3]), o[k * 4 + 3]);                  \
    }                                                                     \
  } while (0)

  // prologue: tile 0 into rA + LDS buf 0
  ISSUE_REL(rA, vbase);
  issue_kv(vbase);
  commit_kv(0);
  PHASE_BARRIER();

  int cur = 0;
  for (int it2 = 0; it2 < 64; ++it2) {
    const int vt = vbase + it2 * 16;
    // ---- phase A: consume rA / buf cur; prefetch tile (2*it2+1) into rB/buf^1
    {
      ISSUE_REL(rB, vt + 8);
      issue_kv(vt + 8);
      COMPUTE(rA, cur);
      commit_kv(cur ^ 1);      // other buffer: its readers finished last barrier
      PHASE_BARRIER();
      cur ^= 1;
    }
    // ---- phase B: consume rB / buf cur; prefetch tile (2*it2+2) into rA/buf^1
    {
      const bool more = (it2 + 1 < 64);
      if (more) {
        ISSUE_REL(rA, vt + 16);
        issue_kv(vt + 16);
      }
      COMPUTE(rB, cur);
      if (more) commit_kv(cur ^ 1);
      PHASE_BARRIER();
      cur ^= 1;
    }
  }

  // ---- reduce-scatter O over the 8 v-lanes: lane vl ends with o[vl*8..+7]
  float n32[32];
#pragma unroll
  for (int j = 0; j < 32; ++j) {
    float send = (vl & 4) ? o[j] : o[j + 32];
    float t = __shfl_xor(send, 16);
    float keep = (vl & 4) ? o[j + 32] : o[j];
    n32[j] = keep + t;
  }
  float n16[16];
#pragma unroll
  for (int j = 0; j < 16; ++j) {
    float send = (vl & 2) ? n32[j] : n32[j + 16];
    float t = __shfl_xor(send, 8);
    float keep = (vl & 2) ? n32[j + 16] : n32[j];
    n16[j] = keep + t;
  }
  float n8[8];
#pragma unroll
  for (int j = 0; j < 8; ++j) {
    float send = (vl & 1) ? n16[j] : n16[j + 8];
    float t = __shfl_xor(send, 4);
    float keep = (vl & 1) ? n16[j + 8] : n16[j];
    n8[j] = keep + t;
  }

  const int orow = (vh * 4 + hq) * 2048 + tg;
  f32x4 w0 = {n8[0], n8[1], n8[2], n8[3]};
  f32x4 w1 = {n8[4], n8[5], n8[6], n8[7]};
  *(f32x4*)&Oh[orow * 64 + vl * 8] = w0;
  *(f32x4*)&Oh[orow * 64 + vl * 8 + 4] = w1;
  if (vl == 0) {
    ml2[orow * 2] = mrun;
    ml2[orow * 2 + 1] = lrun;
  }
#undef ISSUE_REL
#undef COMPUTE
#undef PHASE_BARRIER
}

// ---------------------------------------------------------------------------
// kcomb: merge the two v-half partials.
// O = (c0*O0 + c1*O1) / (c0*l0 + c1*l1), ci = exp(mi - max(m0,m1)).
// ---------------------------------------------------------------------------
__global__ __launch_bounds__(256) void kcomb(
    const float* __restrict__ Oh, const float* __restrict__ ml2,
    float* __restrict__ O) {
  int gid = blockIdx.x * 256 + threadIdx.x;    // 8192 rows * 16 h-quads
  int row = gid >> 4, hc = gid & 15;
  float m0 = ml2[row * 2], l0 = ml2[row * 2 + 1];
  float m1 = ml2[(8192 + row) * 2], l1 = ml2[(8192 + row) * 2 + 1];
  float m = fmaxf(m0, m1);
  float c0 = __expf(m0 - m), c1 = __expf(m1 - m);
  float linv = 1.0f / (c0 * l0 + c1 * l1);
  f32x4 o0 = *(const f32x4*)&Oh[row * 64 + hc * 4];
  f32x4 o1 = *(const f32x4*)&Oh[(8192 + row) * 64 + hc * 4];
  f32x4 r;
#pragma unroll
  for (int j = 0; j < 4; ++j) r[j] = (c0 * o0[j] + c1 * o1[j]) * linv;
  *(f32x4*)&O[row * 64 + hc * 4] = r;
}

// ---------------------------------------------------------------------------
extern "C" void kernel_launch(void* const* d_in, const int* in_sizes, int n_in,
                              void* d_out, int out_size, void* d_ws, size_t ws_size,
                              hipStream_t stream) {
  const float* x   = (const float*)d_in[0];
  const float* wq  = (const float*)d_in[1];
  const float* bq  = (const float*)d_in[2];
  const float* wk  = (const float*)d_in[3];
  const float* bk  = (const float*)d_in[4];
  const float* wv  = (const float*)d_in[5];
  const float* bv  = (const float*)d_in[6];
  const float* rel = (const float*)d_in[7];
  float* O = (float*)d_out;

  char* ws = (char*)d_ws;
  float* qw            = (float*)(ws);                       // 2,097,152 B
  float* k8w           = (float*)(ws + 2097152);             // 2,097,152 B
  unsigned short* vbw  = (unsigned short*)(ws + 4194304);    // 1,048,576 B
  unsigned short* wTh  = (unsigned short*)(ws + 5242880);    //   393,216 B
  unsigned short* wTl  = (unsigned short*)(ws + 5636096);    //   393,216 B
  float* Oh            = (float*)(ws + 6291456);             // 4,194,304 B (2 halves)
  float* ml2           = (float*)(ws + 10485760);            //   131,072 B
  // total ws usage: ~10.6 MB

  kconv_kernel<<<dim3(768), dim3(256), 0, stream>>>(wq, wk, wv, wTh, wTl);
  kproj_kernel<<<dim3(256), dim3(256), 0, stream>>>(x, wTh, wTl, bq, bk, bv, qw, k8w, vbw);
  kfused<<<dim3(512), dim3(256), 0, stream>>>(qw, k8w, vbw, rel, Oh, ml2);
  kcomb<<<dim3(512), dim3(256), 0, stream>>>(Oh, ml2, O);
}